// Round 6
// baseline (206.295 us; speedup 1.0000x reference)
//
#include <hip/hip_runtime.h>
#include <math.h>

#define S_LEN 2048
#define B_SZ 2

typedef __bf16 bf16_8 __attribute__((ext_vector_type(8)));
typedef float  f32_4  __attribute__((ext_vector_type(4)));

__device__ __forceinline__ unsigned short ftob(float f) {
  union { __bf16 h; unsigned short u; } cv;
  cv.h = (__bf16)f;              // fptrunc -> RNE
  return cv.u;
}
__device__ __forceinline__ unsigned int pack2(float a, float b) {
  return (unsigned int)ftob(a) | ((unsigned int)ftob(b) << 16);
}

// async global->LDS, 16B per lane. LDS dest must be wave-uniform base + lane*16.
__device__ __forceinline__ void gll16(const unsigned short* g, unsigned short* l) {
  __builtin_amdgcn_global_load_lds(
      (const __attribute__((address_space(1))) unsigned int*)g,
      (__attribute__((address_space(3))) unsigned int*)l, 16, 0, 0);
}

// fold 1/sqrt(64) * log2(e) into Q at projection -> softmax in exp2 domain
#define QSCALE (0.125f * 1.44269504f)

// ---------------------------------------------------------------------------
// 32x32 transpose+convert tile helper: W[K=1024][N] fp32 -> Wt[N][1024] bf16.
// ---------------------------------------------------------------------------
__device__ __forceinline__ void tr_tile(const float* __restrict__ W,
                                        unsigned short* __restrict__ Wt,
                                        int N, int bx, int by, float (*T)[33])
{
  const int k0 = by * 32, n0 = bx * 32;
  const int r = threadIdx.x >> 3, c4 = (threadIdx.x & 7) * 4;
  const float4 v = *(const float4*)&W[(size_t)(k0 + r) * N + n0 + c4];
  T[r][c4 + 0] = v.x; T[r][c4 + 1] = v.y;
  T[r][c4 + 2] = v.z; T[r][c4 + 3] = v.w;
  __syncthreads();
  ushort4 o;
  o.x = ftob(T[c4 + 0][r]); o.y = ftob(T[c4 + 1][r]);
  o.z = ftob(T[c4 + 2][r]); o.w = ftob(T[c4 + 3][r]);
  *(ushort4*)&Wt[(size_t)(n0 + r) * 1024 + k0 + c4] = o;
}

// ---------------------------------------------------------------------------
// prep: [0,1024) wq->wqkvt | [1024,1280) wk | [1280,1536) wv |
//       [1536,2560) wo->wot | [2560,3584) x fp32->bf16
// ---------------------------------------------------------------------------
__global__ __launch_bounds__(256) void prep(
    const float* __restrict__ x, const float* __restrict__ wq,
    const float* __restrict__ wk, const float* __restrict__ wv,
    const float* __restrict__ wo,
    unsigned short* __restrict__ xb, unsigned short* __restrict__ wqkvt,
    unsigned short* __restrict__ wot)
{
  __shared__ float T[32][33];
  const int idx = blockIdx.x;
  if (idx < 1024) {
    tr_tile(wq, wqkvt, 1024, idx & 31, idx >> 5, T);
  } else if (idx < 1280) {
    const int i = idx - 1024;
    tr_tile(wk, wqkvt + 1024 * 1024, 256, i & 7, i >> 3, T);
  } else if (idx < 1536) {
    const int i = idx - 1280;
    tr_tile(wv, wqkvt + 1280 * 1024, 256, i & 7, i >> 3, T);
  } else if (idx < 2560) {
    const int i = idx - 1536;
    tr_tile(wo, wot, 1024, i & 31, i >> 5, T);
  } else {
    const int i = idx - 2560;
#pragma unroll
    for (int j = 0; j < 4; ++j) {
      const int id = i * 1024 + (int)threadIdx.x + j * 256;
      const float4 v = ((const float4*)x)[id];
      ushort4 o;
      o.x = ftob(v.x); o.y = ftob(v.y); o.z = ftob(v.z); o.w = ftob(v.w);
      ((ushort4*)xb)[id] = o;
    }
  }
}

// ---------------------------------------------------------------------------
// Fused QKV GEMM (unchanged from R5): [4096][1536] = xb @ wqkvt^T.
// BM=64, BN=128, BK=32. Epilogue: Q rope+scale -> qb; K rope -> Kimg;
// V -> LDS transpose -> Vimg.
// ---------------------------------------------------------------------------
__global__ __launch_bounds__(256) void gemm_qkv(
    const unsigned short* __restrict__ A, const unsigned short* __restrict__ Bt,
    unsigned short* __restrict__ qb, unsigned short* __restrict__ Kimg,
    unsigned short* __restrict__ Vimg,
    const float* __restrict__ cosT, const float* __restrict__ sinT)
{
  __shared__ unsigned short sm[9216];
  unsigned short* As = sm;
  unsigned short* Bs = sm + 2048;
  const int bm = blockIdx.y * 64, bn0 = blockIdx.x;
  const int tid = threadIdx.x;
  const int w = tid >> 6, lane = tid & 63, l16 = lane & 15, quad = lane >> 4;
  const int mh = (w & 1) * 32, nh = (w >> 1) * 64;

  f32_4 acc[2][4];
#pragma unroll
  for (int mt = 0; mt < 2; ++mt)
#pragma unroll
    for (int nt = 0; nt < 4; ++nt) acc[mt][nt] = (f32_4){0.f, 0.f, 0.f, 0.f};

  for (int k0 = 0; k0 < 1024; k0 += 32) {
    __syncthreads();
    gll16(&A[(size_t)(bm + (tid >> 2)) * 1024 + k0 + (tid & 3) * 8], &As[tid * 8]);
    gll16(&Bt[(size_t)(bn0 * 128 + (tid >> 2)) * 1024 + k0 + (tid & 3) * 8], &Bs[tid * 8]);
    {
      const int cb = tid + 256;
      gll16(&Bt[(size_t)(bn0 * 128 + (cb >> 2)) * 1024 + k0 + (cb & 3) * 8], &Bs[cb * 8]);
    }
    __syncthreads();
    bf16_8 af[2], bf[4];
#pragma unroll
    for (int mt = 0; mt < 2; ++mt)
      af[mt] = *(const bf16_8*)&As[(mh + mt * 16 + l16) * 32 + quad * 8];
#pragma unroll
    for (int nt = 0; nt < 4; ++nt)
      bf[nt] = *(const bf16_8*)&Bs[(nh + nt * 16 + l16) * 32 + quad * 8];
#pragma unroll
    for (int mt = 0; mt < 2; ++mt)
#pragma unroll
      for (int nt = 0; nt < 4; ++nt)
        acc[mt][nt] = __builtin_amdgcn_mfma_f32_16x16x32_bf16(af[mt], bf[nt], acc[mt][nt], 0, 0, 0);
  }

  const int colbase = bn0 * 128;
  if (colbase < 1024) {            // ---- Q: rope + scale ----
#pragma unroll
    for (int mt = 0; mt < 2; ++mt)
#pragma unroll
      for (int r = 0; r < 4; ++r) {
        const int row = bm + mh + mt * 16 + quad * 4 + r;
        const int s = row & (S_LEN - 1);
#pragma unroll
        for (int nt = 0; nt < 4; ++nt) {
          const int col = colbase + nh + nt * 16 + l16;
          float val = acc[mt][nt][r];
          const float pv = __shfl_xor(val, 1);
          const int fi = (col & 63) >> 1;
          const float cc = cosT[s * 32 + fi], ss = sinT[s * 32 + fi];
          val = (l16 & 1) ? fmaf(pv, ss, val * cc) : fmaf(val, cc, -(pv * ss));
          qb[(size_t)row * 1024 + col] = ftob(val * QSCALE);
        }
      }
  } else if (colbase < 1280) {     // ---- K: rope -> image scatter ----
#pragma unroll
    for (int mt = 0; mt < 2; ++mt)
#pragma unroll
      for (int r = 0; r < 4; ++r) {
        const int row = bm + mh + mt * 16 + quad * 4 + r;
        const int s = row & (S_LEN - 1), bi = row >> 11;
        const int tile = s >> 6, key = s & 63;
#pragma unroll
        for (int nt = 0; nt < 4; ++nt) {
          const int col = colbase + nh + nt * 16 + l16;
          float val = acc[mt][nt][r];
          const float pv = __shfl_xor(val, 1);
          const int fi = (col & 63) >> 1;
          const float cc = cosT[s * 32 + fi], ss = sinT[s * 32 + fi];
          val = (l16 & 1) ? fmaf(pv, ss, val * cc) : fmaf(val, cc, -(pv * ss));
          const int gcol = col - 1024, g = gcol >> 6, d = gcol & 63;
          Kimg[(size_t)((bi * 4 + g) * 32 + tile) * 4608 + key * 72 + d] = ftob(val);
        }
      }
  } else {                         // ---- V: LDS transpose -> image b128 ----
    __syncthreads();
    const int half = nh >> 6;
    unsigned short* Ts = sm + half * 4608;
#pragma unroll
    for (int mt = 0; mt < 2; ++mt)
#pragma unroll
      for (int r = 0; r < 4; ++r) {
        const int key = mh + mt * 16 + quad * 4 + r;
#pragma unroll
        for (int nt = 0; nt < 4; ++nt) {
          const int d = nt * 16 + l16;
          Ts[d * 72 + key] = ftob(acc[mt][nt][r]);
        }
      }
    __syncthreads();
    const int bi = bm >> 11, tile = (bm & 2047) >> 6;
#pragma unroll
    for (int it = 0; it < 4; ++it) {
      const int c = tid + it * 256;
      const int hh = c >> 9, cc = c & 511;
      const int d = cc >> 3, k8 = (cc & 7) * 8;
      const int g = (bn0 - 10) * 2 + hh;
      const uint4 v = *(const uint4*)&sm[hh * 4608 + d * 72 + k8];
      *(uint4*)&Vimg[(size_t)((bi * 4 + g) * 32 + tile) * 4608 + d * 72 + k8] = v;
    }
  }
}

// ---------------------------------------------------------------------------
// Output GEMM (unchanged from R5): out[4096][1024] fp32 = attn @ wot^T.
// ---------------------------------------------------------------------------
__global__ __launch_bounds__(256) void gemm_wo(
    const unsigned short* __restrict__ A, const unsigned short* __restrict__ Bt,
    float* __restrict__ C)
{
  __shared__ unsigned short sm[6144];
  unsigned short* As = sm;
  unsigned short* Bs = sm + 2048;
  const int bm = blockIdx.y * 64, bn0 = blockIdx.x;
  const int tid = threadIdx.x;
  const int w = tid >> 6, lane = tid & 63, l16 = lane & 15, quad = lane >> 4;
  const int mh = (w & 1) * 32, nh = (w >> 1) * 64;

  f32_4 acc[2][4];
#pragma unroll
  for (int mt = 0; mt < 2; ++mt)
#pragma unroll
    for (int nt = 0; nt < 4; ++nt) acc[mt][nt] = (f32_4){0.f, 0.f, 0.f, 0.f};

  for (int k0 = 0; k0 < 1024; k0 += 32) {
    __syncthreads();
    gll16(&A[(size_t)(bm + (tid >> 2)) * 1024 + k0 + (tid & 3) * 8], &As[tid * 8]);
    gll16(&Bt[(size_t)(bn0 * 128 + (tid >> 2)) * 1024 + k0 + (tid & 3) * 8], &Bs[tid * 8]);
    {
      const int cb = tid + 256;
      gll16(&Bt[(size_t)(bn0 * 128 + (cb >> 2)) * 1024 + k0 + (cb & 3) * 8], &Bs[cb * 8]);
    }
    __syncthreads();
    bf16_8 af[2], bf[4];
#pragma unroll
    for (int mt = 0; mt < 2; ++mt)
      af[mt] = *(const bf16_8*)&As[(mh + mt * 16 + l16) * 32 + quad * 8];
#pragma unroll
    for (int nt = 0; nt < 4; ++nt)
      bf[nt] = *(const bf16_8*)&Bs[(nh + nt * 16 + l16) * 32 + quad * 8];
#pragma unroll
    for (int mt = 0; mt < 2; ++mt)
#pragma unroll
      for (int nt = 0; nt < 4; ++nt)
        acc[mt][nt] = __builtin_amdgcn_mfma_f32_16x16x32_bf16(af[mt], bf[nt], acc[mt][nt], 0, 0, 0);
  }
#pragma unroll
  for (int mt = 0; mt < 2; ++mt)
#pragma unroll
    for (int r = 0; r < 4; ++r) {
      const int row = bm + mh + mt * 16 + quad * 4 + r;
#pragma unroll
      for (int nt = 0; nt < 4; ++nt)
        C[(size_t)row * 1024 + bn0 * 128 + nh + nt * 16 + l16] = acc[mt][nt][r];
    }
}

// ---------------------------------------------------------------------------
// Flash attention v3: block = 32 q-rows x ALL 4 heads of one KV group.
// grid (64, 4, 2) = 512 blocks (2/CU), heavy-first. Wave w = head g*4+w.
// K/V tile staged once serves 4 heads (2.4x less LDS traffic per unit).
// Q-frags register-resident across all tiles. P relayout C->B operand done
// IN-REGISTER via shuffles (no Ps LDS array, no bank conflicts, no lgkm dep):
//   B-frag elem j of (quad,H) = P[key=H*32+quad*8+j][q=l16], sourced from
//   quads (quad&1)*2 (+1) register pk[2H+(quad>>1)] -> shuffle both mt
//   candidates, select by quad>>1 post-shuffle.
// O aliases qb: block reads rows [qbase,+32) cols [g*256,+256) at entry only,
// writes same region at exit; regions disjoint across blocks.
// ---------------------------------------------------------------------------
__global__ __launch_bounds__(256) void flash_attn_v3(
    const unsigned short* __restrict__ Q, const unsigned short* __restrict__ Kimg,
    const unsigned short* __restrict__ Vimg, unsigned short* __restrict__ O)
{
  __shared__ unsigned short Ks[64 * 72];       // [key][d]
  __shared__ unsigned short Vs[64 * 72];       // [d][key]
  const int qc = 63 - blockIdx.x;              // heavy first
  const int g = blockIdx.y, b = blockIdx.z;
  const int tid = threadIdx.x;
  const int w = tid >> 6, lane = tid & 63, l16 = lane & 15, quad = lane >> 4;
  const int h = g * 4 + w;
  const int qbase = qc * 32;

  // Q B-frags (register-resident): bq[qf][kh], q = qbase+qf*16+l16
  bf16_8 bq[2][2];
#pragma unroll
  for (int qf = 0; qf < 2; ++qf) {
    const unsigned short* qp =
        Q + ((size_t)(b * S_LEN + qbase + qf * 16 + l16)) * 1024 + h * 64;
    bq[qf][0] = *(const bf16_8*)(qp + quad * 8);
    bq[qf][1] = *(const bf16_8*)(qp + 32 + quad * 8);
  }

  f32_4 acc[2][4];
#pragma unroll
  for (int qf = 0; qf < 2; ++qf)
#pragma unroll
    for (int mt = 0; mt < 4; ++mt) acc[qf][mt] = (f32_4){0.f, 0.f, 0.f, 0.f};
  float l_part[2] = {0.f, 0.f};

  const unsigned short* kim = Kimg + (size_t)((b * 4 + g) * 32) * 4608;
  const unsigned short* vim = Vimg + (size_t)((b * 4 + g) * 32) * 4608;
  const int ntiles = (qc >> 1) + 1;

  for (int tile = 0; tile < ntiles; ++tile) {
    __syncthreads();                           // prev tile fully consumed
    const unsigned short* kp = kim + (size_t)tile * 4608;
    const unsigned short* vp = vim + (size_t)tile * 4608;
#pragma unroll
    for (int i = 0; i < 4; ++i) {
      const int c = tid + i * 256;
      if (c < 576) gll16(kp + c * 8, Ks + c * 8);
      else         gll16(vp + (c - 576) * 8, Vs + (c - 576) * 8);
    }
    if (tid < 128) {
      const int c = tid + 1024;
      gll16(vp + (c - 576) * 8, Vs + (c - 576) * 8);
    }
    __syncthreads();

    const bool diag = (tile == ntiles - 1);
    // ---- QK^T (S^T: row=key, col=q) + exp2 + pack to bf16 pairs ----
    unsigned int pk[2][4][2];
#pragma unroll
    for (int mt = 0; mt < 4; ++mt) {
      const bf16_8 kf0 = *(const bf16_8*)&Ks[(mt * 16 + l16) * 72 + quad * 8];
      const bf16_8 kf1 = *(const bf16_8*)&Ks[(mt * 16 + l16) * 72 + 32 + quad * 8];
#pragma unroll
      for (int qf = 0; qf < 2; ++qf) {
        f32_4 z = (f32_4){0.f, 0.f, 0.f, 0.f};
        z = __builtin_amdgcn_mfma_f32_16x16x32_bf16(kf0, bq[qf][0], z, 0, 0, 0);
        z = __builtin_amdgcn_mfma_f32_16x16x32_bf16(kf1, bq[qf][1], z, 0, 0, 0);
        float p[4];
#pragma unroll
        for (int r = 0; r < 4; ++r) {
          float pv = __builtin_amdgcn_exp2f(z[r]);
          if (diag) {
            const int keyl = mt * 16 + quad * 4 + r;
            const int ql = (qc & 1) * 32 + qf * 16 + l16;
            pv = (keyl > ql) ? 0.f : pv;
          }
          l_part[qf] += pv;
          p[r] = pv;
        }
        pk[qf][mt][0] = pack2(p[0], p[1]);
        pk[qf][mt][1] = pack2(p[2], p[3]);
      }
    }
    // ---- in-register C->B relayout via shuffles ----
    const int srcA = (quad & 1) * 32 + l16;    // lane of quad_s0=(quad&1)*2
    const int srcB = srcA + 16;                // quad_s1
    const bool hiq = (quad >> 1) != 0;         // selects mt' = 2H+1
    bf16_8 pfrag[2][2];
#pragma unroll
    for (int qf = 0; qf < 2; ++qf)
#pragma unroll
      for (int H = 0; H < 2; ++H) {
        const unsigned int lo0 = __shfl((int)pk[qf][2 * H][0], srcA);
        const unsigned int lo1 = __shfl((int)pk[qf][2 * H][1], srcA);
        const unsigned int lo2 = __shfl((int)pk[qf][2 * H][0], srcB);
        const unsigned int lo3 = __shfl((int)pk[qf][2 * H][1], srcB);
        const unsigned int hi0 = __shfl((int)pk[qf][2 * H + 1][0], srcA);
        const unsigned int hi1 = __shfl((int)pk[qf][2 * H + 1][1], srcA);
        const unsigned int hi2 = __shfl((int)pk[qf][2 * H + 1][0], srcB);
        const unsigned int hi3 = __shfl((int)pk[qf][2 * H + 1][1], srcB);
        uint4 u;
        u.x = hiq ? hi0 : lo0;
        u.y = hiq ? hi1 : lo1;
        u.z = hiq ? hi2 : lo2;
        u.w = hiq ? hi3 : lo3;
        pfrag[qf][H] = *(const bf16_8*)&u;
      }
    // ---- O^T += V^T @ P^T ----
#pragma unroll
    for (int mt = 0; mt < 4; ++mt) {
      const bf16_8 vf0 = *(const bf16_8*)&Vs[(mt * 16 + l16) * 72 + quad * 8];
      const bf16_8 vf1 = *(const bf16_8*)&Vs[(mt * 16 + l16) * 72 + 32 + quad * 8];
#pragma unroll
      for (int qf = 0; qf < 2; ++qf) {
        acc[qf][mt] = __builtin_amdgcn_mfma_f32_16x16x32_bf16(vf0, pfrag[qf][0], acc[qf][mt], 0, 0, 0);
        acc[qf][mt] = __builtin_amdgcn_mfma_f32_16x16x32_bf16(vf1, pfrag[qf][1], acc[qf][mt], 0, 0, 0);
      }
    }
  }

  // ---- finalize: l = sum over quads (keys partitioned by quad), write O^T ----
#pragma unroll
  for (int qf = 0; qf < 2; ++qf) {
    float l = l_part[qf];
    l += __shfl_xor(l, 16);
    l += __shfl_xor(l, 32);
    const float inv = 1.f / l;
    unsigned short* op =
        O + ((size_t)(b * S_LEN + qbase + qf * 16 + l16)) * 1024 + h * 64;
#pragma unroll
    for (int mt = 0; mt < 4; ++mt) {
      ushort4 ov;
#pragma unroll
      for (int r = 0; r < 4; ++r) ((unsigned short*)&ov)[r] = ftob(acc[qf][mt][r] * inv);
      *(ushort4*)&op[mt * 16 + quad * 4] = ov;
    }
  }
}

// ---------------------------------------------------------------------------
extern "C" void kernel_launch(void* const* d_in, const int* in_sizes, int n_in,
                              void* d_out, int out_size, void* d_ws, size_t ws_size,
                              hipStream_t stream)
{
  const float* x    = (const float*)d_in[0];
  const float* cosT = (const float*)d_in[1];
  const float* sinT = (const float*)d_in[2];
  const float* wq   = (const float*)d_in[4];
  const float* wk   = (const float*)d_in[5];
  const float* wv   = (const float*)d_in[6];
  const float* wo   = (const float*)d_in[7];
  float* out = (float*)d_out;

  char* ws = (char*)d_ws;
  const size_t MB = 1024 * 1024;
  unsigned short* xb    = (unsigned short*)(ws);                  // 8 MB
  unsigned short* qb    = (unsigned short*)(ws + 8 * MB);         // 8 MB [4096][1024]
  unsigned short* wqkvt = (unsigned short*)(ws + 16 * MB);        // 3 MB [1536][1024]
  unsigned short* Kimg  = (unsigned short*)(ws + 19 * MB);        // 2.25 MB: 256 x [64 key][72]
  unsigned short* Vimg  = (unsigned short*)(ws + 19 * MB + 2359296); // 2.25 MB: 256 x [64 d][72]
  unsigned short* wot   = (unsigned short*)(ws + 24641536);       // 2 MB [1024][1024]
  // total ws use: ~25.5 MB

  prep<<<3584, 256, 0, stream>>>(x, wq, wk, wv, wo, xb, wqkvt, wot);
  gemm_qkv<<<dim3(12, 64), 256, 0, stream>>>(xb, wqkvt, qb, Kimg, Vimg, cosT, sinT);
  flash_attn_v3<<<dim3(64, 4, 2), 256, 0, stream>>>(qb, Kimg, Vimg, qb);
  gemm_wo<<<dim3(8, 64), 256, 0, stream>>>(qb, wot, out);
}

// Round 7
// 204.343 us; speedup vs baseline: 1.0096x; 1.0096x over previous
//
#include <hip/hip_runtime.h>
#include <math.h>

#define S_LEN 2048
#define B_SZ 2

typedef __bf16 bf16_8 __attribute__((ext_vector_type(8)));
typedef float  f32_4  __attribute__((ext_vector_type(4)));

__device__ __forceinline__ unsigned short ftob(float f) {
  union { __bf16 h; unsigned short u; } cv;
  cv.h = (__bf16)f;              // fptrunc -> RNE
  return cv.u;
}
__device__ __forceinline__ unsigned int pack2(float a, float b) {
  return (unsigned int)ftob(a) | ((unsigned int)ftob(b) << 16);
}

// async global->LDS, 16B per lane. LDS dest must be wave-uniform base + lane*16.
__device__ __forceinline__ void gll16(const unsigned short* g, unsigned short* l) {
  __builtin_amdgcn_global_load_lds(
      (const __attribute__((address_space(1))) unsigned int*)g,
      (__attribute__((address_space(3))) unsigned int*)l, 16, 0, 0);
}

// fold 1/sqrt(64) * log2(e) into Q at projection -> softmax in exp2 domain
#define QSCALE (0.125f * 1.44269504f)

// ---------------------------------------------------------------------------
// 32x32 transpose+convert tile helper: W[K=1024][N] fp32 -> Wt[N][1024] bf16.
// ---------------------------------------------------------------------------
__device__ __forceinline__ void tr_tile(const float* __restrict__ W,
                                        unsigned short* __restrict__ Wt,
                                        int N, int bx, int by, float (*T)[33])
{
  const int k0 = by * 32, n0 = bx * 32;
  const int r = threadIdx.x >> 3, c4 = (threadIdx.x & 7) * 4;
  const float4 v = *(const float4*)&W[(size_t)(k0 + r) * N + n0 + c4];
  T[r][c4 + 0] = v.x; T[r][c4 + 1] = v.y;
  T[r][c4 + 2] = v.z; T[r][c4 + 3] = v.w;
  __syncthreads();
  ushort4 o;
  o.x = ftob(T[c4 + 0][r]); o.y = ftob(T[c4 + 1][r]);
  o.z = ftob(T[c4 + 2][r]); o.w = ftob(T[c4 + 3][r]);
  *(ushort4*)&Wt[(size_t)(n0 + r) * 1024 + k0 + c4] = o;
}

// ---------------------------------------------------------------------------
// prep: [0,1024) wq->wqkvt | [1024,1280) wk | [1280,1536) wv |
//       [1536,2560) wo->wot | [2560,3584) x fp32->bf16
// ---------------------------------------------------------------------------
__global__ __launch_bounds__(256) void prep(
    const float* __restrict__ x, const float* __restrict__ wq,
    const float* __restrict__ wk, const float* __restrict__ wv,
    const float* __restrict__ wo,
    unsigned short* __restrict__ xb, unsigned short* __restrict__ wqkvt,
    unsigned short* __restrict__ wot)
{
  __shared__ float T[32][33];
  const int idx = blockIdx.x;
  if (idx < 1024) {
    tr_tile(wq, wqkvt, 1024, idx & 31, idx >> 5, T);
  } else if (idx < 1280) {
    const int i = idx - 1024;
    tr_tile(wk, wqkvt + 1024 * 1024, 256, i & 7, i >> 3, T);
  } else if (idx < 1536) {
    const int i = idx - 1280;
    tr_tile(wv, wqkvt + 1280 * 1024, 256, i & 7, i >> 3, T);
  } else if (idx < 2560) {
    const int i = idx - 1536;
    tr_tile(wo, wot, 1024, i & 31, i >> 5, T);
  } else {
    const int i = idx - 2560;
#pragma unroll
    for (int j = 0; j < 4; ++j) {
      const int id = i * 1024 + (int)threadIdx.x + j * 256;
      const float4 v = ((const float4*)x)[id];
      ushort4 o;
      o.x = ftob(v.x); o.y = ftob(v.y); o.z = ftob(v.z); o.w = ftob(v.w);
      ((ushort4*)xb)[id] = o;
    }
  }
}

// ---------------------------------------------------------------------------
// GEMM staging: A 64 rows (256 chunks), B 128 rows (512 chunks) into one buf.
// buf layout: As[0..2048) | Bs[2048..6144)
// ---------------------------------------------------------------------------
__device__ __forceinline__ void stage_ab(
    const unsigned short* __restrict__ A, const unsigned short* __restrict__ Bt,
    int bm, int bn0, int k0, unsigned short* buf, int tid)
{
  gll16(&A[(size_t)(bm + (tid >> 2)) * 1024 + k0 + (tid & 3) * 8], buf + tid * 8);
  gll16(&Bt[(size_t)(bn0 * 128 + (tid >> 2)) * 1024 + k0 + (tid & 3) * 8],
        buf + 2048 + tid * 8);
  const int cb = tid + 256;
  gll16(&Bt[(size_t)(bn0 * 128 + (cb >> 2)) * 1024 + k0 + (cb & 3) * 8],
        buf + 2048 + cb * 8);
}

// ---------------------------------------------------------------------------
// Fused QKV GEMM: [4096][1536] = xb @ wqkvt^T. BM=64, BN=128, BK=32,
// double-buffered staging, ONE barrier per K-step (prefetch next during
// compute of current). Epilogue: Q rope+scale -> qb; K rope -> Kimg;
// V -> LDS transpose -> Vimg.
// ---------------------------------------------------------------------------
__global__ __launch_bounds__(256) void gemm_qkv(
    const unsigned short* __restrict__ A, const unsigned short* __restrict__ Bt,
    unsigned short* __restrict__ qb, unsigned short* __restrict__ Kimg,
    unsigned short* __restrict__ Vimg,
    const float* __restrict__ cosT, const float* __restrict__ sinT)
{
  __shared__ unsigned short sm[12288];         // 2 x (As 2048 | Bs 4096)
  const int bm = blockIdx.y * 64, bn0 = blockIdx.x;
  const int tid = threadIdx.x;
  const int w = tid >> 6, lane = tid & 63, l16 = lane & 15, quad = lane >> 4;
  const int mh = (w & 1) * 32, nh = (w >> 1) * 64;

  f32_4 acc[2][4];
#pragma unroll
  for (int mt = 0; mt < 2; ++mt)
#pragma unroll
    for (int nt = 0; nt < 4; ++nt) acc[mt][nt] = (f32_4){0.f, 0.f, 0.f, 0.f};

  stage_ab(A, Bt, bm, bn0, 0, sm, tid);
  for (int i = 0; i < 32; ++i) {
    __syncthreads();                           // drains prev stage + guards bufs
    if (i + 1 < 32)
      stage_ab(A, Bt, bm, bn0, (i + 1) * 32, sm + ((i + 1) & 1) * 6144, tid);
    const unsigned short* As = sm + (i & 1) * 6144;
    const unsigned short* Bs = As + 2048;
    bf16_8 af[2], bf[4];
#pragma unroll
    for (int mt = 0; mt < 2; ++mt)
      af[mt] = *(const bf16_8*)&As[(mh + mt * 16 + l16) * 32 + quad * 8];
#pragma unroll
    for (int nt = 0; nt < 4; ++nt)
      bf[nt] = *(const bf16_8*)&Bs[(nh + nt * 16 + l16) * 32 + quad * 8];
#pragma unroll
    for (int mt = 0; mt < 2; ++mt)
#pragma unroll
      for (int nt = 0; nt < 4; ++nt)
        acc[mt][nt] = __builtin_amdgcn_mfma_f32_16x16x32_bf16(af[mt], bf[nt], acc[mt][nt], 0, 0, 0);
  }

  const int colbase = bn0 * 128;
  if (colbase < 1024) {            // ---- Q: rope + scale ----
#pragma unroll
    for (int mt = 0; mt < 2; ++mt)
#pragma unroll
      for (int r = 0; r < 4; ++r) {
        const int row = bm + mh + mt * 16 + quad * 4 + r;
        const int s = row & (S_LEN - 1);
#pragma unroll
        for (int nt = 0; nt < 4; ++nt) {
          const int col = colbase + nh + nt * 16 + l16;
          float val = acc[mt][nt][r];
          const float pv = __shfl_xor(val, 1);
          const int fi = (col & 63) >> 1;
          const float cc = cosT[s * 32 + fi], ss = sinT[s * 32 + fi];
          val = (l16 & 1) ? fmaf(pv, ss, val * cc) : fmaf(val, cc, -(pv * ss));
          qb[(size_t)row * 1024 + col] = ftob(val * QSCALE);
        }
      }
  } else if (colbase < 1280) {     // ---- K: rope -> image scatter ----
#pragma unroll
    for (int mt = 0; mt < 2; ++mt)
#pragma unroll
      for (int r = 0; r < 4; ++r) {
        const int row = bm + mh + mt * 16 + quad * 4 + r;
        const int s = row & (S_LEN - 1), bi = row >> 11;
        const int tile = s >> 6, key = s & 63;
#pragma unroll
        for (int nt = 0; nt < 4; ++nt) {
          const int col = colbase + nh + nt * 16 + l16;
          float val = acc[mt][nt][r];
          const float pv = __shfl_xor(val, 1);
          const int fi = (col & 63) >> 1;
          const float cc = cosT[s * 32 + fi], ss = sinT[s * 32 + fi];
          val = (l16 & 1) ? fmaf(pv, ss, val * cc) : fmaf(val, cc, -(pv * ss));
          const int gcol = col - 1024, g = gcol >> 6, d = gcol & 63;
          Kimg[(size_t)((bi * 4 + g) * 32 + tile) * 4608 + key * 72 + d] = ftob(val);
        }
      }
  } else {                         // ---- V: LDS transpose -> image b128 ----
    __syncthreads();               // As/Bs reads done block-wide before reuse
    const int half = nh >> 6;
    unsigned short* Ts = sm + half * 4608;     // [64 d][72]
#pragma unroll
    for (int mt = 0; mt < 2; ++mt)
#pragma unroll
      for (int r = 0; r < 4; ++r) {
        const int key = mh + mt * 16 + quad * 4 + r;
#pragma unroll
        for (int nt = 0; nt < 4; ++nt) {
          const int d = nt * 16 + l16;
          Ts[d * 72 + key] = ftob(acc[mt][nt][r]);
        }
      }
    __syncthreads();
    const int bi = bm >> 11, tile = (bm & 2047) >> 6;
#pragma unroll
    for (int it = 0; it < 4; ++it) {
      const int c = tid + it * 256;
      const int hh = c >> 9, cc = c & 511;
      const int d = cc >> 3, k8 = (cc & 7) * 8;
      const int g = (bn0 - 10) * 2 + hh;
      const uint4 v = *(const uint4*)&sm[hh * 4608 + d * 72 + k8];
      *(uint4*)&Vimg[(size_t)((bi * 4 + g) * 32 + tile) * 4608 + d * 72 + k8] = v;
    }
  }
}

// ---------------------------------------------------------------------------
// Output GEMM: out[4096][1024] fp32 = attn @ wot^T. Same double-buffered core.
// ---------------------------------------------------------------------------
__global__ __launch_bounds__(256) void gemm_wo(
    const unsigned short* __restrict__ A, const unsigned short* __restrict__ Bt,
    float* __restrict__ C)
{
  __shared__ unsigned short sm[12288];
  const int bm = blockIdx.y * 64, bn0 = blockIdx.x;
  const int tid = threadIdx.x;
  const int w = tid >> 6, lane = tid & 63, l16 = lane & 15, quad = lane >> 4;
  const int mh = (w & 1) * 32, nh = (w >> 1) * 64;

  f32_4 acc[2][4];
#pragma unroll
  for (int mt = 0; mt < 2; ++mt)
#pragma unroll
    for (int nt = 0; nt < 4; ++nt) acc[mt][nt] = (f32_4){0.f, 0.f, 0.f, 0.f};

  stage_ab(A, Bt, bm, bn0, 0, sm, tid);
  for (int i = 0; i < 32; ++i) {
    __syncthreads();
    if (i + 1 < 32)
      stage_ab(A, Bt, bm, bn0, (i + 1) * 32, sm + ((i + 1) & 1) * 6144, tid);
    const unsigned short* As = sm + (i & 1) * 6144;
    const unsigned short* Bs = As + 2048;
    bf16_8 af[2], bf[4];
#pragma unroll
    for (int mt = 0; mt < 2; ++mt)
      af[mt] = *(const bf16_8*)&As[(mh + mt * 16 + l16) * 32 + quad * 8];
#pragma unroll
    for (int nt = 0; nt < 4; ++nt)
      bf[nt] = *(const bf16_8*)&Bs[(nh + nt * 16 + l16) * 32 + quad * 8];
#pragma unroll
    for (int mt = 0; mt < 2; ++mt)
#pragma unroll
      for (int nt = 0; nt < 4; ++nt)
        acc[mt][nt] = __builtin_amdgcn_mfma_f32_16x16x32_bf16(af[mt], bf[nt], acc[mt][nt], 0, 0, 0);
  }
#pragma unroll
  for (int mt = 0; mt < 2; ++mt)
#pragma unroll
    for (int r = 0; r < 4; ++r) {
      const int row = bm + mh + mt * 16 + quad * 4 + r;
#pragma unroll
      for (int nt = 0; nt < 4; ++nt)
        C[(size_t)row * 1024 + bn0 * 128 + nh + nt * 16 + l16] = acc[mt][nt][r];
    }
}

// ---------------------------------------------------------------------------
// K/V tile staging into one double-buffer slot: K image 576 chunks,
// V image 576 chunks. buf layout: Ks[0..4608) | Vs[4608..9216).
// ---------------------------------------------------------------------------
__device__ __forceinline__ void stage_kv(
    const unsigned short* __restrict__ kp, const unsigned short* __restrict__ vp,
    unsigned short* buf, int tid)
{
#pragma unroll
  for (int i = 0; i < 4; ++i) {
    const int c = tid + i * 256;
    if (c < 576) gll16(kp + c * 8, buf + c * 8);
    else         gll16(vp + (c - 576) * 8, buf + 4608 + (c - 576) * 8);
  }
  if (tid < 128) {
    const int c = tid + 448;                   // chunks 448..575 of V
    gll16(vp + c * 8, buf + 4608 + c * 8);
  }
}

// ---------------------------------------------------------------------------
// Flash attention v4 = v3 + double-buffered K/V staging, ONE barrier/tile.
// block = 32 q-rows x all 4 heads of one KV group; grid (64,4,2), heavy-first.
// P relayout C->B operand in-register via shuffles (no Ps LDS).
// O aliases qb: block reads rows [qbase,+32) cols [g*256,+256) at entry only,
// writes same region at exit; regions disjoint across blocks.
// ---------------------------------------------------------------------------
__global__ __launch_bounds__(256) void flash_attn_v4(
    const unsigned short* __restrict__ Q, const unsigned short* __restrict__ Kimg,
    const unsigned short* __restrict__ Vimg, unsigned short* __restrict__ O)
{
  __shared__ unsigned short sm[2][9216];       // [buf][ Ks 4608 | Vs 4608 ]
  const int qc = 63 - blockIdx.x;              // heavy first
  const int g = blockIdx.y, b = blockIdx.z;
  const int tid = threadIdx.x;
  const int w = tid >> 6, lane = tid & 63, l16 = lane & 15, quad = lane >> 4;
  const int h = g * 4 + w;
  const int qbase = qc * 32;

  bf16_8 bq[2][2];
#pragma unroll
  for (int qf = 0; qf < 2; ++qf) {
    const unsigned short* qp =
        Q + ((size_t)(b * S_LEN + qbase + qf * 16 + l16)) * 1024 + h * 64;
    bq[qf][0] = *(const bf16_8*)(qp + quad * 8);
    bq[qf][1] = *(const bf16_8*)(qp + 32 + quad * 8);
  }

  f32_4 acc[2][4];
#pragma unroll
  for (int qf = 0; qf < 2; ++qf)
#pragma unroll
    for (int mt = 0; mt < 4; ++mt) acc[qf][mt] = (f32_4){0.f, 0.f, 0.f, 0.f};
  float l_part[2] = {0.f, 0.f};

  const unsigned short* kim = Kimg + (size_t)((b * 4 + g) * 32) * 4608;
  const unsigned short* vim = Vimg + (size_t)((b * 4 + g) * 32) * 4608;
  const int ntiles = (qc >> 1) + 1;

  stage_kv(kim, vim, sm[0], tid);              // prefetch tile 0
  for (int tile = 0; tile < ntiles; ++tile) {
    __syncthreads();                           // drains my gll; syncs block
    if (tile + 1 < ntiles)
      stage_kv(kim + (size_t)(tile + 1) * 4608, vim + (size_t)(tile + 1) * 4608,
               sm[(tile + 1) & 1], tid);
    const unsigned short* Ks = sm[tile & 1];
    const unsigned short* Vs = sm[tile & 1] + 4608;

    const bool diag = (tile == ntiles - 1);
    // ---- QK^T (S^T: row=key, col=q) + exp2 + pack to bf16 pairs ----
    unsigned int pk[2][4][2];
#pragma unroll
    for (int mt = 0; mt < 4; ++mt) {
      const bf16_8 kf0 = *(const bf16_8*)&Ks[(mt * 16 + l16) * 72 + quad * 8];
      const bf16_8 kf1 = *(const bf16_8*)&Ks[(mt * 16 + l16) * 72 + 32 + quad * 8];
#pragma unroll
      for (int qf = 0; qf < 2; ++qf) {
        f32_4 z = (f32_4){0.f, 0.f, 0.f, 0.f};
        z = __builtin_amdgcn_mfma_f32_16x16x32_bf16(kf0, bq[qf][0], z, 0, 0, 0);
        z = __builtin_amdgcn_mfma_f32_16x16x32_bf16(kf1, bq[qf][1], z, 0, 0, 0);
        float p[4];
#pragma unroll
        for (int r = 0; r < 4; ++r) {
          float pv = __builtin_amdgcn_exp2f(z[r]);
          if (diag) {
            const int keyl = mt * 16 + quad * 4 + r;
            const int ql = (qc & 1) * 32 + qf * 16 + l16;
            pv = (keyl > ql) ? 0.f : pv;
          }
          l_part[qf] += pv;
          p[r] = pv;
        }
        pk[qf][mt][0] = pack2(p[0], p[1]);
        pk[qf][mt][1] = pack2(p[2], p[3]);
      }
    }
    // ---- in-register C->B relayout via shuffles ----
    const int srcA = (quad & 1) * 32 + l16;
    const int srcB = srcA + 16;
    const bool hiq = (quad >> 1) != 0;
    bf16_8 pfrag[2][2];
#pragma unroll
    for (int qf = 0; qf < 2; ++qf)
#pragma unroll
      for (int H = 0; H < 2; ++H) {
        const unsigned int lo0 = __shfl((int)pk[qf][2 * H][0], srcA);
        const unsigned int lo1 = __shfl((int)pk[qf][2 * H][1], srcA);
        const unsigned int lo2 = __shfl((int)pk[qf][2 * H][0], srcB);
        const unsigned int lo3 = __shfl((int)pk[qf][2 * H][1], srcB);
        const unsigned int hi0 = __shfl((int)pk[qf][2 * H + 1][0], srcA);
        const unsigned int hi1 = __shfl((int)pk[qf][2 * H + 1][1], srcA);
        const unsigned int hi2 = __shfl((int)pk[qf][2 * H + 1][0], srcB);
        const unsigned int hi3 = __shfl((int)pk[qf][2 * H + 1][1], srcB);
        uint4 u;
        u.x = hiq ? hi0 : lo0;
        u.y = hiq ? hi1 : lo1;
        u.z = hiq ? hi2 : lo2;
        u.w = hiq ? hi3 : lo3;
        pfrag[qf][H] = *(const bf16_8*)&u;
      }
    // ---- O^T += V^T @ P^T ----
#pragma unroll
    for (int mt = 0; mt < 4; ++mt) {
      const bf16_8 vf0 = *(const bf16_8*)&Vs[(mt * 16 + l16) * 72 + quad * 8];
      const bf16_8 vf1 = *(const bf16_8*)&Vs[(mt * 16 + l16) * 72 + 32 + quad * 8];
#pragma unroll
      for (int qf = 0; qf < 2; ++qf) {
        acc[qf][mt] = __builtin_amdgcn_mfma_f32_16x16x32_bf16(vf0, pfrag[qf][0], acc[qf][mt], 0, 0, 0);
        acc[qf][mt] = __builtin_amdgcn_mfma_f32_16x16x32_bf16(vf1, pfrag[qf][1], acc[qf][mt], 0, 0, 0);
      }
    }
  }

  // ---- finalize ----
#pragma unroll
  for (int qf = 0; qf < 2; ++qf) {
    float l = l_part[qf];
    l += __shfl_xor(l, 16);
    l += __shfl_xor(l, 32);
    const float inv = 1.f / l;
    unsigned short* op =
        O + ((size_t)(b * S_LEN + qbase + qf * 16 + l16)) * 1024 + h * 64;
#pragma unroll
    for (int mt = 0; mt < 4; ++mt) {
      ushort4 ov;
#pragma unroll
      for (int r = 0; r < 4; ++r) ((unsigned short*)&ov)[r] = ftob(acc[qf][mt][r] * inv);
      *(ushort4*)&op[mt * 16 + quad * 4] = ov;
    }
  }
}

// ---------------------------------------------------------------------------
extern "C" void kernel_launch(void* const* d_in, const int* in_sizes, int n_in,
                              void* d_out, int out_size, void* d_ws, size_t ws_size,
                              hipStream_t stream)
{
  const float* x    = (const float*)d_in[0];
  const float* cosT = (const float*)d_in[1];
  const float* sinT = (const float*)d_in[2];
  const float* wq   = (const float*)d_in[4];
  const float* wk   = (const float*)d_in[5];
  const float* wv   = (const float*)d_in[6];
  const float* wo   = (const float*)d_in[7];
  float* out = (float*)d_out;

  char* ws = (char*)d_ws;
  const size_t MB = 1024 * 1024;
  unsigned short* xb    = (unsigned short*)(ws);                  // 8 MB
  unsigned short* qb    = (unsigned short*)(ws + 8 * MB);         // 8 MB [4096][1024]
  unsigned short* wqkvt = (unsigned short*)(ws + 16 * MB);        // 3 MB [1536][1024]
  unsigned short* Kimg  = (unsigned short*)(ws + 19 * MB);        // 2.25 MB: 256 x [64 key][72]
  unsigned short* Vimg  = (unsigned short*)(ws + 19 * MB + 2359296); // 2.25 MB: 256 x [64 d][72]
  unsigned short* wot   = (unsigned short*)(ws + 24641536);       // 2 MB [1024][1024]
  // total ws use: ~25.5 MB

  prep<<<3584, 256, 0, stream>>>(x, wq, wk, wv, wo, xb, wqkvt, wot);
  gemm_qkv<<<dim3(12, 64), 256, 0, stream>>>(xb, wqkvt, qb, Kimg, Vimg, cosT, sinT);
  flash_attn_v4<<<dim3(64, 4, 2), 256, 0, stream>>>(qb, Kimg, Vimg, qb);
  gemm_wo<<<dim3(8, 64), 256, 0, stream>>>(qb, wot, out);
}

// Round 8
// 188.234 us; speedup vs baseline: 1.0960x; 1.0856x over previous
//
#include <hip/hip_runtime.h>
#include <math.h>

#define S_LEN 2048
#define B_SZ 2

typedef __bf16 bf16_8 __attribute__((ext_vector_type(8)));
typedef float  f32_4  __attribute__((ext_vector_type(4)));

__device__ __forceinline__ unsigned short ftob(float f) {
  union { __bf16 h; unsigned short u; } cv;
  cv.h = (__bf16)f;              // fptrunc -> RNE
  return cv.u;
}
__device__ __forceinline__ unsigned int pack2(float a, float b) {
  return (unsigned int)ftob(a) | ((unsigned int)ftob(b) << 16);
}

// fold 1/sqrt(64) * log2(e) into Q at projection -> softmax in exp2 domain
#define QSCALE (0.125f * 1.44269504f)

// ---------------------------------------------------------------------------
// 32x32 transpose+convert tile helper: W[K=1024][N] fp32 -> Wt[N][1024] bf16.
// ---------------------------------------------------------------------------
__device__ __forceinline__ void tr_tile(const float* __restrict__ W,
                                        unsigned short* __restrict__ Wt,
                                        int N, int bx, int by, float (*T)[33])
{
  const int k0 = by * 32, n0 = bx * 32;
  const int r = threadIdx.x >> 3, c4 = (threadIdx.x & 7) * 4;
  const float4 v = *(const float4*)&W[(size_t)(k0 + r) * N + n0 + c4];
  T[r][c4 + 0] = v.x; T[r][c4 + 1] = v.y;
  T[r][c4 + 2] = v.z; T[r][c4 + 3] = v.w;
  __syncthreads();
  ushort4 o;
  o.x = ftob(T[c4 + 0][r]); o.y = ftob(T[c4 + 1][r]);
  o.z = ftob(T[c4 + 2][r]); o.w = ftob(T[c4 + 3][r]);
  *(ushort4*)&Wt[(size_t)(n0 + r) * 1024 + k0 + c4] = o;
}

// ---------------------------------------------------------------------------
// prep: [0,1024) wq->wqkvt | [1024,1280) wk | [1280,1536) wv |
//       [1536,2560) wo->wot | [2560,3584) x fp32->bf16
// ---------------------------------------------------------------------------
__global__ __launch_bounds__(256) void prep(
    const float* __restrict__ x, const float* __restrict__ wq,
    const float* __restrict__ wk, const float* __restrict__ wv,
    const float* __restrict__ wo,
    unsigned short* __restrict__ xb, unsigned short* __restrict__ wqkvt,
    unsigned short* __restrict__ wot)
{
  __shared__ float T[32][33];
  const int idx = blockIdx.x;
  if (idx < 1024) {
    tr_tile(wq, wqkvt, 1024, idx & 31, idx >> 5, T);
  } else if (idx < 1280) {
    const int i = idx - 1024;
    tr_tile(wk, wqkvt + 1024 * 1024, 256, i & 7, i >> 3, T);
  } else if (idx < 1536) {
    const int i = idx - 1280;
    tr_tile(wv, wqkvt + 1280 * 1024, 256, i & 7, i >> 3, T);
  } else if (idx < 2560) {
    const int i = idx - 1536;
    tr_tile(wo, wot, 1024, i & 31, i >> 5, T);
  } else {
    const int i = idx - 2560;
#pragma unroll
    for (int j = 0; j < 4; ++j) {
      const int id = i * 1024 + (int)threadIdx.x + j * 256;
      const float4 v = ((const float4*)x)[id];
      ushort4 o;
      o.x = ftob(v.x); o.y = ftob(v.y); o.z = ftob(v.z); o.w = ftob(v.w);
      ((ushort4*)xb)[id] = o;
    }
  }
}

// ---------------------------------------------------------------------------
// GEMM register-prefetch staging macros. Per thread: 1 A chunk + 2 B chunks.
// Loads land in VGPRs (no LDS-alias vmcnt poison); ds_write after barrier.
// ---------------------------------------------------------------------------
#define GEMM_LOAD_AB(k0)                                                        \
  do {                                                                          \
    ra  = *(const uint4*)&A[(size_t)(bm + (tid >> 2)) * 1024 + (k0) + (tid & 3) * 8]; \
    rb0 = *(const uint4*)&Bt[(size_t)(bn0 * 128 + (tid >> 2)) * 1024 + (k0) + (tid & 3) * 8]; \
    rb1 = *(const uint4*)&Bt[(size_t)(bn0 * 128 + ((tid + 256) >> 2)) * 1024 + (k0) + (tid & 3) * 8]; \
  } while (0)

#define GEMM_STORE_AB()                                                         \
  do {                                                                          \
    *(uint4*)&As[tid * 8] = ra;                                                 \
    *(uint4*)&Bs[tid * 8] = rb0;                                                \
    *(uint4*)&Bs[(tid + 256) * 8] = rb1;                                        \
  } while (0)

#define GEMM_COMPUTE()                                                          \
  do {                                                                          \
    bf16_8 af[2], bf[4];                                                        \
    _Pragma("unroll")                                                           \
    for (int mt = 0; mt < 2; ++mt)                                              \
      af[mt] = *(const bf16_8*)&As[(mh + mt * 16 + l16) * 32 + quad * 8];       \
    _Pragma("unroll")                                                           \
    for (int nt = 0; nt < 4; ++nt)                                              \
      bf[nt] = *(const bf16_8*)&Bs[(nh + nt * 16 + l16) * 32 + quad * 8];       \
    _Pragma("unroll")                                                           \
    for (int mt = 0; mt < 2; ++mt)                                              \
      _Pragma("unroll")                                                         \
      for (int nt = 0; nt < 4; ++nt)                                            \
        acc[mt][nt] = __builtin_amdgcn_mfma_f32_16x16x32_bf16(af[mt], bf[nt], acc[mt][nt], 0, 0, 0); \
  } while (0)

// ---------------------------------------------------------------------------
// Fused QKV GEMM: [4096][1536] = xb @ wqkvt^T. BM=64, BN=128, BK=32,
// register-prefetch pipeline, single LDS buffer. Epilogue: Q rope+scale -> qb;
// K rope -> Kimg; V -> LDS transpose -> Vimg.
// ---------------------------------------------------------------------------
__global__ __launch_bounds__(256) void gemm_qkv(
    const unsigned short* __restrict__ A, const unsigned short* __restrict__ Bt,
    unsigned short* __restrict__ qb, unsigned short* __restrict__ Kimg,
    unsigned short* __restrict__ Vimg,
    const float* __restrict__ cosT, const float* __restrict__ sinT)
{
  __shared__ unsigned short sm[9216];          // staging 6144 | V-epilogue 2x4608
  unsigned short* As = sm;
  unsigned short* Bs = sm + 2048;
  const int bm = blockIdx.y * 64, bn0 = blockIdx.x;
  const int tid = threadIdx.x;
  const int w = tid >> 6, lane = tid & 63, l16 = lane & 15, quad = lane >> 4;
  const int mh = (w & 1) * 32, nh = (w >> 1) * 64;

  f32_4 acc[2][4];
#pragma unroll
  for (int mt = 0; mt < 2; ++mt)
#pragma unroll
    for (int nt = 0; nt < 4; ++nt) acc[mt][nt] = (f32_4){0.f, 0.f, 0.f, 0.f};

  uint4 ra, rb0, rb1;
  GEMM_LOAD_AB(0);
  for (int i = 0; i < 32; ++i) {
    __syncthreads();                           // prev compute done reading LDS
    GEMM_STORE_AB();
    if (i + 1 < 32) GEMM_LOAD_AB((i + 1) * 32);
    __syncthreads();                           // ds_writes visible
    GEMM_COMPUTE();
  }

  const int colbase = bn0 * 128;
  if (colbase < 1024) {            // ---- Q: rope + scale ----
#pragma unroll
    for (int mt = 0; mt < 2; ++mt)
#pragma unroll
      for (int r = 0; r < 4; ++r) {
        const int row = bm + mh + mt * 16 + quad * 4 + r;
        const int s = row & (S_LEN - 1);
#pragma unroll
        for (int nt = 0; nt < 4; ++nt) {
          const int col = colbase + nh + nt * 16 + l16;
          float val = acc[mt][nt][r];
          const float pv = __shfl_xor(val, 1);
          const int fi = (col & 63) >> 1;
          const float cc = cosT[s * 32 + fi], ss = sinT[s * 32 + fi];
          val = (l16 & 1) ? fmaf(pv, ss, val * cc) : fmaf(val, cc, -(pv * ss));
          qb[(size_t)row * 1024 + col] = ftob(val * QSCALE);
        }
      }
  } else if (colbase < 1280) {     // ---- K: rope -> image scatter ----
#pragma unroll
    for (int mt = 0; mt < 2; ++mt)
#pragma unroll
      for (int r = 0; r < 4; ++r) {
        const int row = bm + mh + mt * 16 + quad * 4 + r;
        const int s = row & (S_LEN - 1), bi = row >> 11;
        const int tile = s >> 6, key = s & 63;
#pragma unroll
        for (int nt = 0; nt < 4; ++nt) {
          const int col = colbase + nh + nt * 16 + l16;
          float val = acc[mt][nt][r];
          const float pv = __shfl_xor(val, 1);
          const int fi = (col & 63) >> 1;
          const float cc = cosT[s * 32 + fi], ss = sinT[s * 32 + fi];
          val = (l16 & 1) ? fmaf(pv, ss, val * cc) : fmaf(val, cc, -(pv * ss));
          const int gcol = col - 1024, g = gcol >> 6, d = gcol & 63;
          Kimg[(size_t)((bi * 4 + g) * 32 + tile) * 4608 + key * 72 + d] = ftob(val);
        }
      }
  } else {                         // ---- V: LDS transpose -> image b128 ----
    __syncthreads();               // LDS reads done block-wide before reuse
    const int half = nh >> 6;
    unsigned short* Ts = sm + half * 4608;     // [64 d][72]
#pragma unroll
    for (int mt = 0; mt < 2; ++mt)
#pragma unroll
      for (int r = 0; r < 4; ++r) {
        const int key = mh + mt * 16 + quad * 4 + r;
#pragma unroll
        for (int nt = 0; nt < 4; ++nt) {
          const int d = nt * 16 + l16;
          Ts[d * 72 + key] = ftob(acc[mt][nt][r]);
        }
      }
    __syncthreads();
    const int bi = bm >> 11, tile = (bm & 2047) >> 6;
#pragma unroll
    for (int it = 0; it < 4; ++it) {
      const int c = tid + it * 256;
      const int hh = c >> 9, cc = c & 511;
      const int d = cc >> 3, k8 = (cc & 7) * 8;
      const int g = (bn0 - 10) * 2 + hh;
      const uint4 v = *(const uint4*)&sm[hh * 4608 + d * 72 + k8];
      *(uint4*)&Vimg[(size_t)((bi * 4 + g) * 32 + tile) * 4608 + d * 72 + k8] = v;
    }
  }
}

// ---------------------------------------------------------------------------
// Output GEMM: out[4096][1024] fp32 = attn @ wot^T. Same reg-prefetch core.
// ---------------------------------------------------------------------------
__global__ __launch_bounds__(256) void gemm_wo(
    const unsigned short* __restrict__ A, const unsigned short* __restrict__ Bt,
    float* __restrict__ C)
{
  __shared__ unsigned short sm[6144];
  unsigned short* As = sm;
  unsigned short* Bs = sm + 2048;
  const int bm = blockIdx.y * 64, bn0 = blockIdx.x;
  const int tid = threadIdx.x;
  const int w = tid >> 6, lane = tid & 63, l16 = lane & 15, quad = lane >> 4;
  const int mh = (w & 1) * 32, nh = (w >> 1) * 64;

  f32_4 acc[2][4];
#pragma unroll
  for (int mt = 0; mt < 2; ++mt)
#pragma unroll
    for (int nt = 0; nt < 4; ++nt) acc[mt][nt] = (f32_4){0.f, 0.f, 0.f, 0.f};

  uint4 ra, rb0, rb1;
  GEMM_LOAD_AB(0);
  for (int i = 0; i < 32; ++i) {
    __syncthreads();
    GEMM_STORE_AB();
    if (i + 1 < 32) GEMM_LOAD_AB((i + 1) * 32);
    __syncthreads();
    GEMM_COMPUTE();
  }
#pragma unroll
  for (int mt = 0; mt < 2; ++mt)
#pragma unroll
    for (int r = 0; r < 4; ++r) {
      const int row = bm + mh + mt * 16 + quad * 4 + r;
#pragma unroll
      for (int nt = 0; nt < 4; ++nt)
        C[(size_t)row * 1024 + bn0 * 128 + nh + nt * 16 + l16] = acc[mt][nt][r];
    }
}

// ---------------------------------------------------------------------------
// Flash attention v5 = v3 compute + (a) XCD-pinned (b,g) via id&7 (round-robin
// block->XCD), (b) anti-correlated qc pairing so co-resident blocks (i, i+256)
// sum to exactly 33 tiles, (c) register-prefetch K/V staging (global->VGPR,
// ds_write after barrier) -- avoids the global_load_lds vmcnt(0) serialization.
// block = 32 q-rows x all 4 heads of one KV group; grid 512 (1-D).
// Per-XCD L2 footprint: KV 0.6 MB + Q 1 MB (one (b,g)) -> L2-resident.
// O aliases qb: block reads rows [qbase,+32) cols [g*256,+256) at entry only,
// writes same region at exit; regions disjoint across blocks.
// ---------------------------------------------------------------------------
__global__ __launch_bounds__(256) void flash_attn_v5(
    const unsigned short* __restrict__ Q, const unsigned short* __restrict__ Kimg,
    const unsigned short* __restrict__ Vimg, unsigned short* __restrict__ O)
{
  __shared__ unsigned short Ks[64 * 72];       // [key][d]
  __shared__ unsigned short Vs[64 * 72];       // [d][key]
  const int id = blockIdx.x;
  const int gb = id & 7;                       // b*4+g -> XCD pin
  const int g = gb & 3, b = gb >> 2;
  const int j = id >> 3;                       // 0..63
  const int qc = (j < 32) ? (63 - j) : (j - 32);   // pair sums to 33 tiles
  const int tid = threadIdx.x;
  const int w = tid >> 6, lane = tid & 63, l16 = lane & 15, quad = lane >> 4;
  const int h = g * 4 + w;
  const int qbase = qc * 32;

  bf16_8 bq[2][2];
#pragma unroll
  for (int qf = 0; qf < 2; ++qf) {
    const unsigned short* qp =
        Q + ((size_t)(b * S_LEN + qbase + qf * 16 + l16)) * 1024 + h * 64;
    bq[qf][0] = *(const bf16_8*)(qp + quad * 8);
    bq[qf][1] = *(const bf16_8*)(qp + 32 + quad * 8);
  }

  f32_4 acc[2][4];
#pragma unroll
  for (int qf = 0; qf < 2; ++qf)
#pragma unroll
    for (int mt = 0; mt < 4; ++mt) acc[qf][mt] = (f32_4){0.f, 0.f, 0.f, 0.f};
  float l_part[2] = {0.f, 0.f};

  const unsigned short* kim = Kimg + (size_t)(gb * 32) * 4608;
  const unsigned short* vim = Vimg + (size_t)(gb * 32) * 4608;
  const int ntiles = (qc >> 1) + 1;

  // K image = chunks [0,576), V image = chunks [576,1152); thread tid owns
  // chunks tid, tid+256, tid+512, tid+768 (+ tid+1024 for tid<128).
  uint4 r0, r1, r2, r3, r4;
#define FA_LOAD(t)                                                              \
  do {                                                                          \
    const unsigned short* kp = kim + (size_t)(t) * 4608;                        \
    const unsigned short* vp = vim + (size_t)(t) * 4608;                        \
    r0 = *(const uint4*)(kp + tid * 8);                                         \
    r1 = *(const uint4*)(kp + (tid + 256) * 8);                                 \
    r2 = (tid < 64) ? *(const uint4*)(kp + (tid + 512) * 8)                     \
                    : *(const uint4*)(vp + (tid - 64) * 8);                     \
    r3 = *(const uint4*)(vp + (tid + 192) * 8);                                 \
    if (tid < 128) r4 = *(const uint4*)(vp + (tid + 448) * 8);                  \
  } while (0)
#define FA_STORE()                                                              \
  do {                                                                          \
    *(uint4*)(Ks + tid * 8) = r0;                                               \
    *(uint4*)(Ks + (tid + 256) * 8) = r1;                                       \
    if (tid < 64) *(uint4*)(Ks + (tid + 512) * 8) = r2;                         \
    else          *(uint4*)(Vs + (tid - 64) * 8) = r2;                          \
    *(uint4*)(Vs + (tid + 192) * 8) = r3;                                       \
    if (tid < 128) *(uint4*)(Vs + (tid + 448) * 8) = r4;                        \
  } while (0)

  FA_LOAD(0);
  for (int tile = 0; tile < ntiles; ++tile) {
    __syncthreads();                           // prev compute done reading LDS
    FA_STORE();
    if (tile + 1 < ntiles) FA_LOAD(tile + 1);
    __syncthreads();                           // ds_writes visible

    const bool diag = (tile == ntiles - 1);
    // ---- QK^T (S^T: row=key, col=q) + exp2 + pack to bf16 pairs ----
    unsigned int pk[2][4][2];
#pragma unroll
    for (int mt = 0; mt < 4; ++mt) {
      const bf16_8 kf0 = *(const bf16_8*)&Ks[(mt * 16 + l16) * 72 + quad * 8];
      const bf16_8 kf1 = *(const bf16_8*)&Ks[(mt * 16 + l16) * 72 + 32 + quad * 8];
#pragma unroll
      for (int qf = 0; qf < 2; ++qf) {
        f32_4 z = (f32_4){0.f, 0.f, 0.f, 0.f};
        z = __builtin_amdgcn_mfma_f32_16x16x32_bf16(kf0, bq[qf][0], z, 0, 0, 0);
        z = __builtin_amdgcn_mfma_f32_16x16x32_bf16(kf1, bq[qf][1], z, 0, 0, 0);
        float p[4];
#pragma unroll
        for (int r = 0; r < 4; ++r) {
          float pv = __builtin_amdgcn_exp2f(z[r]);
          if (diag) {
            const int keyl = mt * 16 + quad * 4 + r;
            const int ql = (qc & 1) * 32 + qf * 16 + l16;
            pv = (keyl > ql) ? 0.f : pv;
          }
          l_part[qf] += pv;
          p[r] = pv;
        }
        pk[qf][mt][0] = pack2(p[0], p[1]);
        pk[qf][mt][1] = pack2(p[2], p[3]);
      }
    }
    // ---- in-register C->B relayout via shuffles ----
    const int srcA = (quad & 1) * 32 + l16;
    const int srcB = srcA + 16;
    const bool hiq = (quad >> 1) != 0;
    bf16_8 pfrag[2][2];
#pragma unroll
    for (int qf = 0; qf < 2; ++qf)
#pragma unroll
      for (int H = 0; H < 2; ++H) {
        const unsigned int lo0 = __shfl((int)pk[qf][2 * H][0], srcA);
        const unsigned int lo1 = __shfl((int)pk[qf][2 * H][1], srcA);
        const unsigned int lo2 = __shfl((int)pk[qf][2 * H][0], srcB);
        const unsigned int lo3 = __shfl((int)pk[qf][2 * H][1], srcB);
        const unsigned int hi0 = __shfl((int)pk[qf][2 * H + 1][0], srcA);
        const unsigned int hi1 = __shfl((int)pk[qf][2 * H + 1][1], srcA);
        const unsigned int hi2 = __shfl((int)pk[qf][2 * H + 1][0], srcB);
        const unsigned int hi3 = __shfl((int)pk[qf][2 * H + 1][1], srcB);
        uint4 u;
        u.x = hiq ? hi0 : lo0;
        u.y = hiq ? hi1 : lo1;
        u.z = hiq ? hi2 : lo2;
        u.w = hiq ? hi3 : lo3;
        pfrag[qf][H] = *(const bf16_8*)&u;
      }
    // ---- O^T += V^T @ P^T ----
#pragma unroll
    for (int mt = 0; mt < 4; ++mt) {
      const bf16_8 vf0 = *(const bf16_8*)&Vs[(mt * 16 + l16) * 72 + quad * 8];
      const bf16_8 vf1 = *(const bf16_8*)&Vs[(mt * 16 + l16) * 72 + 32 + quad * 8];
#pragma unroll
      for (int qf = 0; qf < 2; ++qf) {
        acc[qf][mt] = __builtin_amdgcn_mfma_f32_16x16x32_bf16(vf0, pfrag[qf][0], acc[qf][mt], 0, 0, 0);
        acc[qf][mt] = __builtin_amdgcn_mfma_f32_16x16x32_bf16(vf1, pfrag[qf][1], acc[qf][mt], 0, 0, 0);
      }
    }
  }

  // ---- finalize: l = sum over quads (keys partitioned by quad), write O^T ----
#pragma unroll
  for (int qf = 0; qf < 2; ++qf) {
    float l = l_part[qf];
    l += __shfl_xor(l, 16);
    l += __shfl_xor(l, 32);
    const float inv = 1.f / l;
    unsigned short* op =
        O + ((size_t)(b * S_LEN + qbase + qf * 16 + l16)) * 1024 + h * 64;
#pragma unroll
    for (int mt = 0; mt < 4; ++mt) {
      ushort4 ov;
#pragma unroll
      for (int r = 0; r < 4; ++r) ((unsigned short*)&ov)[r] = ftob(acc[qf][mt][r] * inv);
      *(ushort4*)&op[mt * 16 + quad * 4] = ov;
    }
  }
}

// ---------------------------------------------------------------------------
extern "C" void kernel_launch(void* const* d_in, const int* in_sizes, int n_in,
                              void* d_out, int out_size, void* d_ws, size_t ws_size,
                              hipStream_t stream)
{
  const float* x    = (const float*)d_in[0];
  const float* cosT = (const float*)d_in[1];
  const float* sinT = (const float*)d_in[2];
  const float* wq   = (const float*)d_in[4];
  const float* wk   = (const float*)d_in[5];
  const float* wv   = (const float*)d_in[6];
  const float* wo   = (const float*)d_in[7];
  float* out = (float*)d_out;

  char* ws = (char*)d_ws;
  const size_t MB = 1024 * 1024;
  unsigned short* xb    = (unsigned short*)(ws);                  // 8 MB
  unsigned short* qb    = (unsigned short*)(ws + 8 * MB);         // 8 MB [4096][1024]
  unsigned short* wqkvt = (unsigned short*)(ws + 16 * MB);        // 3 MB [1536][1024]
  unsigned short* Kimg  = (unsigned short*)(ws + 19 * MB);        // 2.25 MB: 256 x [64 key][72]
  unsigned short* Vimg  = (unsigned short*)(ws + 19 * MB + 2359296); // 2.25 MB: 256 x [64 d][72]
  unsigned short* wot   = (unsigned short*)(ws + 24641536);       // 2 MB [1024][1024]
  // total ws use: ~25.5 MB

  prep<<<3584, 256, 0, stream>>>(x, wq, wk, wv, wo, xb, wqkvt, wot);
  gemm_qkv<<<dim3(12, 64), 256, 0, stream>>>(xb, wqkvt, qb, Kimg, Vimg, cosT, sinT);
  flash_attn_v5<<<512, 256, 0, stream>>>(qb, Kimg, Vimg, qb);
  gemm_wo<<<dim3(8, 64), 256, 0, stream>>>(qb, wot, out);
}

// Round 9
// 183.515 us; speedup vs baseline: 1.1241x; 1.0257x over previous
//
#include <hip/hip_runtime.h>
#include <math.h>

#define S_LEN 2048
#define B_SZ 2

typedef __bf16 bf16_8 __attribute__((ext_vector_type(8)));
typedef float  f32_4  __attribute__((ext_vector_type(4)));

__device__ __forceinline__ unsigned short ftob(float f) {
  union { __bf16 h; unsigned short u; } cv;
  cv.h = (__bf16)f;              // fptrunc -> RNE
  return cv.u;
}

// async global->LDS, 16B per lane. LDS dest must be wave-uniform base + lane*16.
__device__ __forceinline__ void gll16(const unsigned short* g, unsigned short* l) {
  __builtin_amdgcn_global_load_lds(
      (const __attribute__((address_space(1))) unsigned int*)g,
      (__attribute__((address_space(3))) unsigned int*)l, 16, 0, 0);
}

// fold 1/sqrt(64) * log2(e) into Q at projection -> softmax in exp2 domain
#define QSCALE (0.125f * 1.44269504f)

// K/V tile images: dense 64x64 bf16 (4096 shorts = 8 KB), 16B-chunk XOR
// swizzle: element (row, col) at row*64 + ((col>>3) ^ (row&7))*8 + (col&7).
// K image rows = key, cols = d. V image rows = d, cols = key.

// ---------------------------------------------------------------------------
// 32x32 transpose+convert tile helper: W[K=1024][N] fp32 -> Wt[N][1024] bf16.
// ---------------------------------------------------------------------------
__device__ __forceinline__ void tr_tile(const float* __restrict__ W,
                                        unsigned short* __restrict__ Wt,
                                        int N, int bx, int by, float (*T)[33])
{
  const int k0 = by * 32, n0 = bx * 32;
  const int r = threadIdx.x >> 3, c4 = (threadIdx.x & 7) * 4;
  const float4 v = *(const float4*)&W[(size_t)(k0 + r) * N + n0 + c4];
  T[r][c4 + 0] = v.x; T[r][c4 + 1] = v.y;
  T[r][c4 + 2] = v.z; T[r][c4 + 3] = v.w;
  __syncthreads();
  ushort4 o;
  o.x = ftob(T[c4 + 0][r]); o.y = ftob(T[c4 + 1][r]);
  o.z = ftob(T[c4 + 2][r]); o.w = ftob(T[c4 + 3][r]);
  *(ushort4*)&Wt[(size_t)(n0 + r) * 1024 + k0 + c4] = o;
}

// ---------------------------------------------------------------------------
// prep: [0,1024) wq->wqkvt | [1024,1280) wk | [1280,1536) wv |
//       [1536,2560) wo->wot | [2560,3584) x fp32->bf16
// ---------------------------------------------------------------------------
__global__ __launch_bounds__(256) void prep(
    const float* __restrict__ x, const float* __restrict__ wq,
    const float* __restrict__ wk, const float* __restrict__ wv,
    const float* __restrict__ wo,
    unsigned short* __restrict__ xb, unsigned short* __restrict__ wqkvt,
    unsigned short* __restrict__ wot)
{
  __shared__ float T[32][33];
  const int idx = blockIdx.x;
  if (idx < 1024) {
    tr_tile(wq, wqkvt, 1024, idx & 31, idx >> 5, T);
  } else if (idx < 1280) {
    const int i = idx - 1024;
    tr_tile(wk, wqkvt + 1024 * 1024, 256, i & 7, i >> 3, T);
  } else if (idx < 1536) {
    const int i = idx - 1280;
    tr_tile(wv, wqkvt + 1280 * 1024, 256, i & 7, i >> 3, T);
  } else if (idx < 2560) {
    const int i = idx - 1536;
    tr_tile(wo, wot, 1024, i & 31, i >> 5, T);
  } else {
    const int i = idx - 2560;
#pragma unroll
    for (int j = 0; j < 4; ++j) {
      const int id = i * 1024 + (int)threadIdx.x + j * 256;
      const float4 v = ((const float4*)x)[id];
      ushort4 o;
      o.x = ftob(v.x); o.y = ftob(v.y); o.z = ftob(v.z); o.w = ftob(v.w);
      ((ushort4*)xb)[id] = o;
    }
  }
}

// ---------------------------------------------------------------------------
// m97-style 128x128 GEMM core: BK=32, global_load_lds w16, unpadded LDS,
// 2 barriers per K-step. As = sm[0..4096), Bs = sm[4096..8192) shorts.
// ---------------------------------------------------------------------------
#define G128_KLOOP(A_, B_)                                                      \
  for (int k0 = 0; k0 < 1024; k0 += 32) {                                       \
    __syncthreads();                                                            \
    {                                                                           \
      const int r = tid >> 2, o8 = (tid & 3) * 8;                               \
      gll16(&A_[(size_t)(bm + r) * 1024 + k0 + o8], &sm[tid * 8]);              \
      gll16(&A_[(size_t)(bm + r + 64) * 1024 + k0 + o8], &sm[(tid + 256) * 8]); \
      gll16(&B_[(size_t)(bn0 * 128 + r) * 1024 + k0 + o8], &sm[4096 + tid * 8]);\
      gll16(&B_[(size_t)(bn0 * 128 + r + 64) * 1024 + k0 + o8],                 \
            &sm[4096 + (tid + 256) * 8]);                                       \
    }                                                                           \
    __syncthreads();                                                            \
    bf16_8 af[4], bf[4];                                                        \
    _Pragma("unroll")                                                           \
    for (int mt = 0; mt < 4; ++mt)                                              \
      af[mt] = *(const bf16_8*)&sm[(mh + mt * 16 + l16) * 32 + quad * 8];       \
    _Pragma("unroll")                                                           \
    for (int nt = 0; nt < 4; ++nt)                                              \
      bf[nt] = *(const bf16_8*)&sm[4096 + (nh + nt * 16 + l16) * 32 + quad * 8];\
    _Pragma("unroll")                                                           \
    for (int mt = 0; mt < 4; ++mt)                                              \
      _Pragma("unroll")                                                         \
      for (int nt = 0; nt < 4; ++nt)                                            \
        acc[mt][nt] = __builtin_amdgcn_mfma_f32_16x16x32_bf16(af[mt], bf[nt],   \
                                                              acc[mt][nt], 0, 0, 0); \
  }

// ---------------------------------------------------------------------------
// Fused QKV GEMM: [4096][1536] = xb @ wqkvt^T. BM=BN=128, grid (12,32).
// Epilogue by column block: bn0 0..7 Q rope+scale -> qb; 8..9 K rope -> Kimg
// (swizzled); 10..11 V -> LDS transpose -> Vimg (swizzled, b128 stores).
// ---------------------------------------------------------------------------
__global__ __launch_bounds__(256) void gemm_qkv(
    const unsigned short* __restrict__ A, const unsigned short* __restrict__ Bt,
    unsigned short* __restrict__ qb, unsigned short* __restrict__ Kimg,
    unsigned short* __restrict__ Vimg,
    const float* __restrict__ cosT, const float* __restrict__ sinT)
{
  __shared__ unsigned short sm[9216];   // staging 8192 | V-epilogue Ts 2x4608
  const int bm = blockIdx.y * 128, bn0 = blockIdx.x;
  const int tid = threadIdx.x;
  const int w = tid >> 6, lane = tid & 63, l16 = lane & 15, quad = lane >> 4;
  const int mh = (w & 1) * 64, nh = (w >> 1) * 64;

  f32_4 acc[4][4];
#pragma unroll
  for (int mt = 0; mt < 4; ++mt)
#pragma unroll
    for (int nt = 0; nt < 4; ++nt) acc[mt][nt] = (f32_4){0.f, 0.f, 0.f, 0.f};

  G128_KLOOP(A, Bt);

  const int colbase = bn0 * 128;
  if (colbase < 1024) {            // ---- Q: rope + scale ----
#pragma unroll
    for (int mt = 0; mt < 4; ++mt)
#pragma unroll
      for (int r = 0; r < 4; ++r) {
        const int row = bm + mh + mt * 16 + quad * 4 + r;
        const int s = row & (S_LEN - 1);
#pragma unroll
        for (int nt = 0; nt < 4; ++nt) {
          const int col = colbase + nh + nt * 16 + l16;
          float val = acc[mt][nt][r];
          const float pv = __shfl_xor(val, 1);
          const int fi = (col & 63) >> 1;
          const float cc = cosT[s * 32 + fi], ss = sinT[s * 32 + fi];
          val = (l16 & 1) ? fmaf(pv, ss, val * cc) : fmaf(val, cc, -(pv * ss));
          qb[(size_t)row * 1024 + col] = ftob(val * QSCALE);
        }
      }
  } else if (colbase < 1280) {     // ---- K: rope -> swizzled image scatter ----
#pragma unroll
    for (int mt = 0; mt < 4; ++mt)
#pragma unroll
      for (int r = 0; r < 4; ++r) {
        const int row = bm + mh + mt * 16 + quad * 4 + r;
        const int s = row & (S_LEN - 1), bi = row >> 11;
        const int tile = s >> 6, key = s & 63;
#pragma unroll
        for (int nt = 0; nt < 4; ++nt) {
          const int col = colbase + nh + nt * 16 + l16;
          float val = acc[mt][nt][r];
          const float pv = __shfl_xor(val, 1);
          const int fi = (col & 63) >> 1;
          const float cc = cosT[s * 32 + fi], ss = sinT[s * 32 + fi];
          val = (l16 & 1) ? fmaf(pv, ss, val * cc) : fmaf(val, cc, -(pv * ss));
          const int gcol = col - 1024, g = gcol >> 6, d = gcol & 63;
          Kimg[(size_t)((bi * 4 + g) * 32 + tile) * 4096 + key * 64 +
               (((d >> 3) ^ (key & 7)) * 8) + (d & 7)] = ftob(val);
        }
      }
  } else {                         // ---- V: LDS transpose -> swizzled image ----
    const int bi = bm >> 11, t0 = (bm & 2047) >> 6;
    const int gp = (bn0 - 10) * 2;
#pragma unroll
    for (int pass = 0; pass < 2; ++pass) {
      __syncthreads();             // staging reads / prev pass copy done
      if ((w >> 1) == pass) {      // wave handles g = gp+pass, tilehalf = w&1
        unsigned short* Ts = sm + (w & 1) * 4608;   // [64 d][72]
#pragma unroll
        for (int mt = 0; mt < 4; ++mt)
#pragma unroll
          for (int nt = 0; nt < 4; ++nt) {
            const int keyb = mt * 16 + quad * 4;    // 4 consecutive keys
            const int d = nt * 16 + l16;
            ushort4 pk;
#pragma unroll
            for (int r = 0; r < 4; ++r) ((unsigned short*)&pk)[r] = ftob(acc[mt][nt][r]);
            *(ushort4*)&Ts[d * 72 + keyb] = pk;
          }
      }
      __syncthreads();
      const int g = gp + pass;
#pragma unroll
      for (int it = 0; it < 4; ++it) {
        const int c = tid + it * 256;              // 1024 chunks: 2 imgs x 512
        const int img = c >> 9, cc = c & 511;
        const int d = cc >> 3, ch = cc & 7;
        const uint4 v = *(const uint4*)&sm[img * 4608 + d * 72 + ch * 8];
        *(uint4*)&Vimg[(size_t)((bi * 4 + g) * 32 + t0 + img) * 4096 + d * 64 +
                       ((ch ^ (d & 7)) * 8)] = v;
      }
    }
  }
}

// ---------------------------------------------------------------------------
// Output GEMM: out[4096][1024] fp32 = attn @ wot^T. BM=BN=128, grid (8,32).
// ---------------------------------------------------------------------------
__global__ __launch_bounds__(256) void gemm_wo(
    const unsigned short* __restrict__ A, const unsigned short* __restrict__ Bt,
    float* __restrict__ C)
{
  __shared__ unsigned short sm[8192];
  const int bm = blockIdx.y * 128, bn0 = blockIdx.x;
  const int tid = threadIdx.x;
  const int w = tid >> 6, lane = tid & 63, l16 = lane & 15, quad = lane >> 4;
  const int mh = (w & 1) * 64, nh = (w >> 1) * 64;

  f32_4 acc[4][4];
#pragma unroll
  for (int mt = 0; mt < 4; ++mt)
#pragma unroll
    for (int nt = 0; nt < 4; ++nt) acc[mt][nt] = (f32_4){0.f, 0.f, 0.f, 0.f};

  G128_KLOOP(A, Bt);

#pragma unroll
  for (int mt = 0; mt < 4; ++mt)
#pragma unroll
    for (int r = 0; r < 4; ++r) {
      const int row = bm + mh + mt * 16 + quad * 4 + r;
#pragma unroll
      for (int nt = 0; nt < 4; ++nt)
        C[(size_t)row * 1024 + bn0 * 128 + nh + nt * 16 + l16] = acc[mt][nt][r];
    }
}

// ---------------------------------------------------------------------------
// Flash attention v6: XCD-pinned, reg-prefetch staging, dense swizzled K/V
// tiles, Ps LDS roundtrip (per-wave private, swizzled -> conflict-free).
// block = 32 q-rows x all 4 heads of one KV group; grid 512 (2/CU).
// gb = id&7 pins (b,g) to one XCD; co-resident pair sums to 33 tiles.
// O aliases qb: block reads rows [qbase,+32) cols [g*256,+256) at entry only,
// writes same region at exit; regions disjoint across blocks.
// ---------------------------------------------------------------------------
__global__ __launch_bounds__(256) void flash_attn_v6(
    const unsigned short* __restrict__ Q, const unsigned short* __restrict__ Kimg,
    const unsigned short* __restrict__ Vimg, unsigned short* __restrict__ O)
{
  __shared__ unsigned short Ks[4096];          // [key][d] swizzled
  __shared__ unsigned short Vs[4096];          // [d][key] swizzled
  __shared__ unsigned short Ps[4][2048];       // per-wave [32 q][64 key] swizzled
  const int id = blockIdx.x;
  const int gb = id & 7;                       // b*4+g -> XCD pin
  const int g = gb & 3, b = gb >> 2;
  const int j = id >> 3;                       // 0..63
  const int qc = (j < 32) ? (63 - j) : (j - 32);   // pair sums to 33 tiles
  const int tid = threadIdx.x;
  const int w = tid >> 6, lane = tid & 63, l16 = lane & 15, quad = lane >> 4;
  const int h = g * 4 + w;
  const int qbase = qc * 32;
  const int swz = l16 & 7;
  unsigned short* ps = Ps[w];

  // Q B-frags (register-resident): n = q = l16 (+16*qf), k = d = quad*8+j
  bf16_8 bq[2][2];
#pragma unroll
  for (int qf = 0; qf < 2; ++qf) {
    const unsigned short* qp =
        Q + ((size_t)(b * S_LEN + qbase + qf * 16 + l16)) * 1024 + h * 64;
    bq[qf][0] = *(const bf16_8*)(qp + quad * 8);
    bq[qf][1] = *(const bf16_8*)(qp + 32 + quad * 8);
  }

  f32_4 acc[2][4];
#pragma unroll
  for (int qf = 0; qf < 2; ++qf)
#pragma unroll
    for (int mt = 0; mt < 4; ++mt) acc[qf][mt] = (f32_4){0.f, 0.f, 0.f, 0.f};
  float l_part[2] = {0.f, 0.f};

  const unsigned short* kim = Kimg + (size_t)(gb * 32) * 4096;
  const unsigned short* vim = Vimg + (size_t)(gb * 32) * 4096;
  const int ntiles = (qc >> 1) + 1;

  // staging: 512 chunks K + 512 chunks V; thread owns chunks tid, tid+256
  uint4 r0, r1, r2, r3;
#define FA_LOAD(t)                                                              \
  do {                                                                          \
    const unsigned short* kp = kim + (size_t)(t) * 4096;                        \
    const unsigned short* vp = vim + (size_t)(t) * 4096;                        \
    r0 = *(const uint4*)(kp + tid * 8);                                         \
    r1 = *(const uint4*)(kp + (tid + 256) * 8);                                 \
    r2 = *(const uint4*)(vp + tid * 8);                                         \
    r3 = *(const uint4*)(vp + (tid + 256) * 8);                                 \
  } while (0)
#define FA_STORE()                                                              \
  do {                                                                          \
    *(uint4*)(Ks + tid * 8) = r0;                                               \
    *(uint4*)(Ks + (tid + 256) * 8) = r1;                                       \
    *(uint4*)(Vs + tid * 8) = r2;                                               \
    *(uint4*)(Vs + (tid + 256) * 8) = r3;                                       \
  } while (0)

  FA_LOAD(0);
  for (int tile = 0; tile < ntiles; ++tile) {
    __syncthreads();                           // prev compute done reading LDS
    FA_STORE();
    if (tile + 1 < ntiles) FA_LOAD(tile + 1);
    __syncthreads();                           // ds_writes visible

    const bool diag = (tile == ntiles - 1);
    // ---- S^T = K Q^T (row=key, col=q), p = exp2(s), write Ps (b64) ----
#pragma unroll
    for (int mt = 0; mt < 4; ++mt) {
      const int krow = (mt * 16 + l16) * 64;
      const bf16_8 kf0 = *(const bf16_8*)&Ks[krow + (quad ^ swz) * 8];
      const bf16_8 kf1 = *(const bf16_8*)&Ks[krow + ((4 + quad) ^ swz) * 8];
#pragma unroll
      for (int qf = 0; qf < 2; ++qf) {
        f32_4 z = (f32_4){0.f, 0.f, 0.f, 0.f};
        z = __builtin_amdgcn_mfma_f32_16x16x32_bf16(kf0, bq[qf][0], z, 0, 0, 0);
        z = __builtin_amdgcn_mfma_f32_16x16x32_bf16(kf1, bq[qf][1], z, 0, 0, 0);
        ushort4 pk;
#pragma unroll
        for (int r = 0; r < 4; ++r) {
          float pv = __builtin_amdgcn_exp2f(z[r]);
          if (diag) {
            const int keyl = mt * 16 + quad * 4 + r;
            const int ql = (qc & 1) * 32 + qf * 16 + l16;
            pv = (keyl > ql) ? 0.f : pv;
          }
          l_part[qf] += pv;
          ((unsigned short*)&pk)[r] = ftob(pv);
        }
        // q-row qf*16+l16, keys mt*16+quad*4.. -> chunk 2mt+(quad>>1), swizzled
        *(ushort4*)&ps[(qf * 16 + l16) * 64 +
                       (((2 * mt + (quad >> 1)) ^ swz) * 8) + (quad & 1) * 4] = pk;
      }
    }
    // ---- P B-frags from Ps (per-wave private; in-wave lgkm ordering) ----
    bf16_8 pf[2][2];
#pragma unroll
    for (int qf = 0; qf < 2; ++qf) {
      const int prow = (qf * 16 + l16) * 64;
      pf[qf][0] = *(const bf16_8*)&ps[prow + ((quad ^ swz) * 8)];
      pf[qf][1] = *(const bf16_8*)&ps[prow + (((4 + quad) ^ swz) * 8)];
    }
    // ---- O^T += V^T @ P^T ----
#pragma unroll
    for (int mt = 0; mt < 4; ++mt) {
      const int vrow = (mt * 16 + l16) * 64;
      const bf16_8 vf0 = *(const bf16_8*)&Vs[vrow + (quad ^ swz) * 8];
      const bf16_8 vf1 = *(const bf16_8*)&Vs[vrow + ((4 + quad) ^ swz) * 8];
#pragma unroll
      for (int qf = 0; qf < 2; ++qf) {
        acc[qf][mt] = __builtin_amdgcn_mfma_f32_16x16x32_bf16(vf0, pf[qf][0], acc[qf][mt], 0, 0, 0);
        acc[qf][mt] = __builtin_amdgcn_mfma_f32_16x16x32_bf16(vf1, pf[qf][1], acc[qf][mt], 0, 0, 0);
      }
    }
  }

  // ---- finalize: l = sum over quads (keys partitioned by quad), write O^T ----
#pragma unroll
  for (int qf = 0; qf < 2; ++qf) {
    float l = l_part[qf];
    l += __shfl_xor(l, 16);
    l += __shfl_xor(l, 32);
    const float inv = 1.f / l;
    unsigned short* op =
        O + ((size_t)(b * S_LEN + qbase + qf * 16 + l16)) * 1024 + h * 64;
#pragma unroll
    for (int mt = 0; mt < 4; ++mt) {
      ushort4 ov;
#pragma unroll
      for (int r = 0; r < 4; ++r) ((unsigned short*)&ov)[r] = ftob(acc[qf][mt][r] * inv);
      *(ushort4*)&op[mt * 16 + quad * 4] = ov;
    }
  }
}

// ---------------------------------------------------------------------------
extern "C" void kernel_launch(void* const* d_in, const int* in_sizes, int n_in,
                              void* d_out, int out_size, void* d_ws, size_t ws_size,
                              hipStream_t stream)
{
  const float* x    = (const float*)d_in[0];
  const float* cosT = (const float*)d_in[1];
  const float* sinT = (const float*)d_in[2];
  const float* wq   = (const float*)d_in[4];
  const float* wk   = (const float*)d_in[5];
  const float* wv   = (const float*)d_in[6];
  const float* wo   = (const float*)d_in[7];
  float* out = (float*)d_out;

  char* ws = (char*)d_ws;
  const size_t MB = 1024 * 1024;
  unsigned short* xb    = (unsigned short*)(ws);             // 8 MB
  unsigned short* qb    = (unsigned short*)(ws + 8 * MB);    // 8 MB [4096][1024]
  unsigned short* wqkvt = (unsigned short*)(ws + 16 * MB);   // 3 MB [1536][1024]
  unsigned short* Kimg  = (unsigned short*)(ws + 19 * MB);   // 2 MB: 256 x 4096 (swizzled)
  unsigned short* Vimg  = (unsigned short*)(ws + 21 * MB);   // 2 MB: 256 x 4096 (swizzled)
  unsigned short* wot   = (unsigned short*)(ws + 23 * MB);   // 2 MB [1024][1024]
  // total ws use: 25 MB

  prep<<<3584, 256, 0, stream>>>(x, wq, wk, wv, wo, xb, wqkvt, wot);
  gemm_qkv<<<dim3(12, 32), 256, 0, stream>>>(xb, wqkvt, qb, Kimg, Vimg, cosT, sinT);
  flash_attn_v6<<<512, 256, 0, stream>>>(qb, Kimg, Vimg, qb);
  gemm_wo<<<dim3(8, 32), 256, 0, stream>>>(qb, wot, out);
}